// Round 4
// baseline (275.852 us; speedup 1.0000x reference)
//
#include <hip/hip_runtime.h>
#include <hip/hip_bf16.h>

#define LOG2E 1.44269504088896340736f

typedef __attribute__((ext_vector_type(8))) short short8;
typedef __attribute__((ext_vector_type(4))) float floatx4;

static __device__ __forceinline__ short f2bf(float f) {
    union { float f; unsigned u; } v; v.f = f;
    unsigned r = (v.u + 0x7FFF + ((v.u >> 16) & 1)) >> 16;  // RNE
    return (short)r;
}

static __device__ __forceinline__ floatx4 mfma16(short8 a, short8 b, floatx4 c) {
    return __builtin_amdgcn_mfma_f32_16x16x32_bf16(a, b, c, 0, 0, 0);
}

static __device__ __forceinline__ unsigned cvt_pk_bf16(float lo, float hi) {
    unsigned u;
    asm("v_cvt_pk_bf16_f32 %0, %1, %2" : "=v"(u) : "v"(lo), "v"(hi));
    return u;
}

// ---------------- Weight pre-convert: wb[576][512] bf16 ----------------
// rows 0-31 = wq * LOG2E, 32-63 = wk, 64-575 = wv.
__global__ __launch_bounds__(256) void wcvt_kernel(
    const float* __restrict__ wq, const float* __restrict__ wk,
    const float* __restrict__ wv, short* __restrict__ wb)
{
    const int idx = (blockIdx.x * 256 + threadIdx.x) * 4;   // 288*256*4 = 294912 exact
    const int row = idx >> 9;
    const int col = idx & 511;
    const float* src;
    float sc = 1.0f;
    if (row < 32)      { src = wq + (size_t)row * 512; sc = LOG2E; }
    else if (row < 64) { src = wk + (size_t)(row - 32) * 512; }
    else               { src = wv + (size_t)(row - 64) * 512; }
    floatx4 v = *(const floatx4*)(src + col);
    union { short s[4]; long long ll; } o;
#pragma unroll
    for (int u = 0; u < 4; u++) o.s[u] = f2bf(v[u] * sc);
    *(long long*)(wb + idx) = o.ll;
}

// ---------------- Projection: load x tile ONCE, loop all 9 o-tiles ----------------
// grid (64 n-tiles, B), block 256 (4 waves). x HBM read exactly once (32 MB).
// q stored [B][N][32] (LOG2E folded via wb); kT [B][N][32] rows permuted for the
// attn P->PV register pass; v [B][512][N].
__global__ __launch_bounds__(256) void proj_kernel(
    const float* __restrict__ x, const short* __restrict__ wb,
    const float* __restrict__ bq, const float* __restrict__ bk,
    const float* __restrict__ bv,
    short* __restrict__ qT, short* __restrict__ kT, short* __restrict__ vm)
{
    __shared__ short xT[64 * 520];   // [n][c], pitch 520 shorts (odd*16B rows)
    const int tid = threadIdx.x;
    const int w = tid >> 6;
    const int lane = tid & 63;
    const int l15 = lane & 15, l4 = lane >> 4;
    const int n0 = blockIdx.x * 64;
    const int b  = blockIdx.y;

    const float* xb = x + (size_t)b * 512 * 4096;

    // stage full [512c][64n] tile as bf16 [n][c]
#pragma unroll 4
    for (int p = 0; p < 32; p++) {
        const int c = 16 * p + (tid >> 4);
        const int nr = (tid & 15) * 4;
        floatx4 xv = *(const floatx4*)(xb + (size_t)c * 4096 + n0 + nr);
#pragma unroll
        for (int u = 0; u < 4; u++) xT[(nr + u) * 520 + c] = f2bf(xv[u]);
    }
    __syncthreads();

#pragma unroll 1
    for (int ot = 0; ot < 9; ot++) {
        const short* wrow = wb + (size_t)(ot * 64 + w * 16 + l15) * 512;
        floatx4 acc[4];
#pragma unroll
        for (int i = 0; i < 4; i++) acc[i] = (floatx4)(0.0f);

#pragma unroll 4
        for (int c0 = 0; c0 < 512; c0 += 32) {
            short8 af = *(const short8*)(wrow + c0 + 8 * l4);
#pragma unroll
            for (int nt = 0; nt < 4; nt++) {
                short8 bf = *(const short8*)&xT[(nt * 16 + l15) * 520 + c0 + 8 * l4];
                acc[nt] = mfma16(af, bf, acc[nt]);
            }
        }

#pragma unroll
        for (int r = 0; r < 4; r++) {
            const int o_d = ot * 64 + w * 16 + 4 * l4 + r;
#pragma unroll
            for (int nt = 0; nt < 4; nt++) {
                const int n = n0 + nt * 16 + l15;
                const float val = acc[nt][r];
                if (o_d < 32) {
                    qT[((size_t)(b * 4096 + n)) * 32 + o_d] = f2bf(val + bq[o_d] * LOG2E);
                } else if (o_d < 64) {
                    const int s = n & 31;
                    const int p = 16 * ((s >> 2) & 1) + 4 * (s >> 3) + (s & 3);
                    const int nst = (n & ~31) | p;
                    kT[((size_t)(b * 4096 + nst)) * 32 + (o_d - 32)] = f2bf(val + bk[o_d - 32]);
                } else {
                    vm[((size_t)(b * 512 + (o_d - 64))) * 4096 + n] = f2bf(val + bv[o_d - 64]);
                }
            }
        }
    }
}

// ---------------- Flash attention + residual ----------------
// 512 blocks x 4 waves. Block = (b, c-half, q-tile of 64); wave covers 64 c.
// j-macro-tile = 128 (wave w produces j in [w*32, w*32+32)), double-buffered P
// in LDS (32 KB), one barrier per macro-tile. Next-tile K loads issued before
// the PV consume phase so global latency hides under 64 MFMAs.
__global__ __launch_bounds__(256, 4) void attn_kernel(
    const short* __restrict__ qT, const short* __restrict__ kT,
    const short* __restrict__ vm, const float* __restrict__ x,
    const float* __restrict__ gamma, float* __restrict__ out)
{
    __shared__ short P_lds[2][16 * 512];
    __shared__ float red_lds[4 * 64];
    const int tid = threadIdx.x;
    const int lane = tid & 63;
    const int w = tid >> 6;
    const int l15 = lane & 15, l4 = lane >> 4;

    // XCD decode: xcd = b*2 + c-half -> per-XCD V slice 2 MB (L2-resident)
    const int bid = blockIdx.x;
    const int xcd = bid & 7;
    const int qt  = bid >> 3;          // 0..63
    const int b   = xcd >> 1;
    const int ch  = xcd & 1;
    const int i0  = qt * 64;
    const int cb  = ch * 256 + w * 64;

    short8 qf[4];
#pragma unroll
    for (int it = 0; it < 4; it++)
        qf[it] = *(const short8*)(qT + ((size_t)(b * 4096 + i0 + it * 16 + l15)) * 32 + 8 * l4);

    floatx4 acc[4][4];   // [ct][it]
#pragma unroll
    for (int ct = 0; ct < 4; ct++)
#pragma unroll
        for (int it = 0; it < 4; it++) acc[ct][it] = (floatx4)(0.0f);

    float l_[4];
#pragma unroll
    for (int it = 0; it < 4; it++) l_[it] = 0.0f;

    const short* kb = kT + (size_t)b * 4096 * 32;
    const short* vb = vm + (size_t)b * 512 * 4096;

#define PROD(T, KF0, KF1)                                                            \
    {                                                                                \
        const int buf = (T) & 1;                                                     \
        _Pragma("unroll")                                                            \
        for (int it = 0; it < 4; it++) {                                             \
            floatx4 s0 = mfma16((KF0), qf[it], (floatx4)(0.0f));                     \
            floatx4 s1 = mfma16((KF1), qf[it], (floatx4)(0.0f));                     \
            float p[8];                                                              \
            _Pragma("unroll")                                                        \
            for (int r = 0; r < 4; r++) {                                            \
                p[r]     = __builtin_amdgcn_exp2f(s0[r]);                            \
                p[4 + r] = __builtin_amdgcn_exp2f(s1[r]);                            \
            }                                                                        \
            union { short8 s; unsigned u[4]; } pk;                                   \
            _Pragma("unroll")                                                        \
            for (int j2 = 0; j2 < 4; j2++) pk.u[j2] = cvt_pk_bf16(p[2*j2], p[2*j2+1]); \
            *(short8*)&P_lds[buf][(w * 4 + it) * 512 + lane * 8] = pk.s;             \
            l_[it] += ((p[0] + p[1]) + (p[2] + p[3])) + ((p[4] + p[5]) + (p[6] + p[7])); \
        }                                                                            \
    }

#define CONSUME(T)                                                                   \
    {                                                                                \
        const int buf = (T) & 1;                                                     \
        _Pragma("unroll")                                                            \
        for (int jg = 0; jg < 4; jg++) {                                             \
            short8 pcf[4];                                                           \
            _Pragma("unroll")                                                        \
            for (int it = 0; it < 4; it++)                                           \
                pcf[it] = *(const short8*)&P_lds[buf][(jg * 4 + it) * 512 + lane * 8]; \
            _Pragma("unroll")                                                        \
            for (int ct = 0; ct < 4; ct++) {                                         \
                short8 vf = *(const short8*)(vb + (size_t)(cb + ct * 16 + l15) * 4096 \
                                             + (T) * 128 + jg * 32 + 8 * l4);        \
                _Pragma("unroll")                                                    \
                for (int it = 0; it < 4; it++)                                       \
                    acc[ct][it] = mfma16(vf, pcf[it], acc[ct][it]);                  \
            }                                                                        \
        }                                                                            \
    }

    // prologue: produce macro-tile 0
    short8 kf0 = *(const short8*)(kb + (size_t)(w * 32 + l15) * 32 + 8 * l4);
    short8 kf1 = *(const short8*)(kb + (size_t)(w * 32 + 16 + l15) * 32 + 8 * l4);
    PROD(0, kf0, kf1);

#pragma unroll 1
    for (int t = 0; t < 31; t++) {
        __syncthreads();
        const int jj = (t + 1) * 128 + w * 32;
        short8 nk0 = *(const short8*)(kb + (size_t)(jj + l15) * 32 + 8 * l4);
        short8 nk1 = *(const short8*)(kb + (size_t)(jj + 16 + l15) * 32 + 8 * l4);
        CONSUME(t);
        PROD(t + 1, nk0, nk1);
    }
    __syncthreads();
    CONSUME(31);
#undef PROD
#undef CONSUME

    // l: in-lane partials -> cross-l4 reduce -> cross-wave via LDS
#pragma unroll
    for (int it = 0; it < 4; it++) {
        l_[it] += __shfl_xor(l_[it], 16, 64);
        l_[it] += __shfl_xor(l_[it], 32, 64);
    }
    if (lane < 16)
#pragma unroll
        for (int it = 0; it < 4; it++) red_lds[w * 64 + it * 16 + lane] = l_[it];
    __syncthreads();

    const float g = gamma[0];
    float inv[4];
#pragma unroll
    for (int it = 0; it < 4; it++) {
        float s = 0.0f;
#pragma unroll
        for (int ww = 0; ww < 4; ww++) s += red_lds[ww * 64 + it * 16 + l15];
        inv[it] = g / s;
    }

#pragma unroll
    for (int ct = 0; ct < 4; ct++)
#pragma unroll
        for (int it = 0; it < 4; it++)
#pragma unroll
            for (int r = 0; r < 4; r++) {
                const int c = cb + ct * 16 + 4 * l4 + r;
                const int i = i0 + it * 16 + l15;
                const size_t o = ((size_t)(b * 512 + c)) * 4096 + i;
                out[o] = acc[ct][it][r] * inv[it] + x[o];
            }
}

extern "C" void kernel_launch(void* const* d_in, const int* in_sizes, int n_in,
                              void* d_out, int out_size, void* d_ws, size_t ws_size,
                              hipStream_t stream) {
    const float* x     = (const float*)d_in[0];
    const float* wq    = (const float*)d_in[1];
    const float* bq    = (const float*)d_in[2];
    const float* wk    = (const float*)d_in[3];
    const float* bk    = (const float*)d_in[4];
    const float* wv    = (const float*)d_in[5];
    const float* bv    = (const float*)d_in[6];
    const float* gamma = (const float*)d_in[7];
    float* out = (float*)d_out;

    short* qT = (short*)d_ws;                  // 1 MB
    short* kT = qT + (size_t)4 * 4096 * 32;    // 1 MB
    short* vm = kT + (size_t)4 * 4096 * 32;    // 16 MB
    short* wb = vm + (size_t)4 * 512 * 4096;   // 576*512 bf16 = 0.56 MB

    wcvt_kernel<<<288, 256, 0, stream>>>(wq, wk, wv, wb);
    proj_kernel<<<dim3(64, 4), 256, 0, stream>>>(x, wb, bq, bk, bv, qT, kT, vm);
    attn_kernel<<<512, 256, 0, stream>>>(qT, kT, vm, x, gamma, out);
}

// Round 5
// 224.483 us; speedup vs baseline: 1.2288x; 1.2288x over previous
//
#include <hip/hip_runtime.h>
#include <hip/hip_bf16.h>

#define LOG2E 1.44269504088896340736f

typedef __attribute__((ext_vector_type(8))) short short8;
typedef __attribute__((ext_vector_type(4))) float floatx4;

static __device__ __forceinline__ short f2bf(float f) {
    union { float f; unsigned u; } v; v.f = f;
    unsigned r = (v.u + 0x7FFF + ((v.u >> 16) & 1)) >> 16;  // RNE
    return (short)r;
}

static __device__ __forceinline__ floatx4 mfma16(short8 a, short8 b, floatx4 c) {
    return __builtin_amdgcn_mfma_f32_16x16x32_bf16(a, b, c, 0, 0, 0);
}

static __device__ __forceinline__ unsigned cvt_pk_bf16(float lo, float hi) {
    unsigned u;
    asm("v_cvt_pk_bf16_f32 %0, %1, %2" : "=v"(u) : "v"(lo), "v"(hi));
    return u;
}

// ---------------- Weight pre-convert: wb[576][512] bf16 ----------------
__global__ __launch_bounds__(256) void wcvt_kernel(
    const float* __restrict__ wq, const float* __restrict__ wk,
    const float* __restrict__ wv, short* __restrict__ wb)
{
    const int idx = (blockIdx.x * 256 + threadIdx.x) * 4;
    const int row = idx >> 9;
    const int col = idx & 511;
    const float* src;
    float sc = 1.0f;
    if (row < 32)      { src = wq + (size_t)row * 512; sc = LOG2E; }
    else if (row < 64) { src = wk + (size_t)(row - 32) * 512; }
    else               { src = wv + (size_t)(row - 64) * 512; }
    floatx4 v = *(const floatx4*)(src + col);
    union { short s[4]; long long ll; } o;
#pragma unroll
    for (int u = 0; u < 4; u++) o.s[u] = f2bf(v[u] * sc);
    *(long long*)(wb + idx) = o.ll;
}

// ---------------- Projection ----------------
// grid (64 n-tiles, 3 o-groups, B), block 256 (4 waves). Each block stages its
// x tile once in LDS, computes 3 o-tiles (x HBM read 3x total = 96 MB).
__global__ __launch_bounds__(256) void proj_kernel(
    const float* __restrict__ x, const short* __restrict__ wb,
    const float* __restrict__ bq, const float* __restrict__ bk,
    const float* __restrict__ bv,
    short* __restrict__ qT, short* __restrict__ kT, short* __restrict__ vm)
{
    __shared__ short xT[64 * 520];   // [n][c] bf16
    const int tid = threadIdx.x;
    const int w = tid >> 6;
    const int lane = tid & 63;
    const int l15 = lane & 15, l4 = lane >> 4;
    const int n0 = blockIdx.x * 64;
    const int og = blockIdx.y;       // o-group: ot = og*3 .. og*3+2
    const int b  = blockIdx.z;

    const float* xb = x + (size_t)b * 512 * 4096;

#pragma unroll 4
    for (int p = 0; p < 32; p++) {
        const int c = 16 * p + (tid >> 4);
        const int nr = (tid & 15) * 4;
        floatx4 xv = *(const floatx4*)(xb + (size_t)c * 4096 + n0 + nr);
#pragma unroll
        for (int u = 0; u < 4; u++) xT[(nr + u) * 520 + c] = f2bf(xv[u]);
    }
    __syncthreads();

#pragma unroll 1
    for (int oi = 0; oi < 3; oi++) {
        const int ot = og * 3 + oi;
        const short* wrow = wb + (size_t)(ot * 64 + w * 16 + l15) * 512;
        floatx4 acc[4];
#pragma unroll
        for (int i = 0; i < 4; i++) acc[i] = (floatx4)(0.0f);

#pragma unroll 4
        for (int c0 = 0; c0 < 512; c0 += 32) {
            short8 af = *(const short8*)(wrow + c0 + 8 * l4);
#pragma unroll
            for (int nt = 0; nt < 4; nt++) {
                short8 bf = *(const short8*)&xT[(nt * 16 + l15) * 520 + c0 + 8 * l4];
                acc[nt] = mfma16(af, bf, acc[nt]);
            }
        }

#pragma unroll
        for (int r = 0; r < 4; r++) {
            const int o_d = ot * 64 + w * 16 + 4 * l4 + r;
#pragma unroll
            for (int nt = 0; nt < 4; nt++) {
                const int n = n0 + nt * 16 + l15;
                const float val = acc[nt][r];
                if (o_d < 32) {
                    qT[((size_t)(b * 4096 + n)) * 32 + o_d] = f2bf(val + bq[o_d] * LOG2E);
                } else if (o_d < 64) {
                    const int s = n & 31;
                    const int p = 16 * ((s >> 2) & 1) + 4 * (s >> 3) + (s & 3);
                    const int nst = (n & ~31) | p;
                    kT[((size_t)(b * 4096 + nst)) * 32 + (o_d - 32)] = f2bf(val + bk[o_d - 32]);
                } else {
                    vm[((size_t)(b * 512 + (o_d - 64))) * 4096 + n] = f2bf(val + bv[o_d - 64]);
                }
            }
        }
    }
}

// ---------------- Flash attention + residual ----------------
// 512 blocks x 4 waves. Block = (b, c-half, q-tile of 64); wave covers 64 c.
// j-macro-tile = 128, double-buffered P in LDS (32 KB), one barrier per tile.
// NO launch_bounds min-waves hint (R3's (256,4) forced VGPR=64 -> spills).
__global__ __launch_bounds__(256) void attn_kernel(
    const short* __restrict__ qT, const short* __restrict__ kT,
    const short* __restrict__ vm, const float* __restrict__ x,
    const float* __restrict__ gamma, float* __restrict__ out)
{
    __shared__ short P_lds[2][16 * 512];
    __shared__ float red_lds[4 * 64];
    const int tid = threadIdx.x;
    const int lane = tid & 63;
    const int w = tid >> 6;
    const int l15 = lane & 15, l4 = lane >> 4;

    const int bid = blockIdx.x;
    const int xcd = bid & 7;
    const int qt  = bid >> 3;
    const int b   = xcd >> 1;
    const int ch  = xcd & 1;
    const int i0  = qt * 64;
    const int cb  = ch * 256 + w * 64;

    short8 qf[4];
#pragma unroll
    for (int it = 0; it < 4; it++)
        qf[it] = *(const short8*)(qT + ((size_t)(b * 4096 + i0 + it * 16 + l15)) * 32 + 8 * l4);

    floatx4 acc[4][4];
#pragma unroll
    for (int ct = 0; ct < 4; ct++)
#pragma unroll
        for (int it = 0; it < 4; it++) acc[ct][it] = (floatx4)(0.0f);

    float l_[4];
#pragma unroll
    for (int it = 0; it < 4; it++) l_[it] = 0.0f;

    const short* kb = kT + (size_t)b * 4096 * 32;
    const short* vb = vm + (size_t)b * 512 * 4096;

#define PROD(T, KF0, KF1)                                                            \
    {                                                                                \
        const int buf = (T) & 1;                                                     \
        _Pragma("unroll")                                                            \
        for (int it = 0; it < 4; it++) {                                             \
            floatx4 s0 = mfma16((KF0), qf[it], (floatx4)(0.0f));                     \
            floatx4 s1 = mfma16((KF1), qf[it], (floatx4)(0.0f));                     \
            float p[8];                                                              \
            _Pragma("unroll")                                                        \
            for (int r = 0; r < 4; r++) {                                            \
                p[r]     = __builtin_amdgcn_exp2f(s0[r]);                            \
                p[4 + r] = __builtin_amdgcn_exp2f(s1[r]);                            \
            }                                                                        \
            union { short8 s; unsigned u[4]; } pk;                                   \
            _Pragma("unroll")                                                        \
            for (int j2 = 0; j2 < 4; j2++) pk.u[j2] = cvt_pk_bf16(p[2*j2], p[2*j2+1]); \
            *(short8*)&P_lds[buf][(w * 4 + it) * 512 + lane * 8] = pk.s;             \
            l_[it] += ((p[0] + p[1]) + (p[2] + p[3])) + ((p[4] + p[5]) + (p[6] + p[7])); \
        }                                                                            \
    }

#define CONSUME(T)                                                                   \
    {                                                                                \
        const int buf = (T) & 1;                                                     \
        _Pragma("unroll")                                                            \
        for (int jg = 0; jg < 4; jg++) {                                             \
            short8 pcf[4];                                                           \
            _Pragma("unroll")                                                        \
            for (int it = 0; it < 4; it++)                                           \
                pcf[it] = *(const short8*)&P_lds[buf][(jg * 4 + it) * 512 + lane * 8]; \
            _Pragma("unroll")                                                        \
            for (int ct = 0; ct < 4; ct++) {                                         \
                short8 vf = *(const short8*)(vb + (size_t)(cb + ct * 16 + l15) * 4096 \
                                             + (T) * 128 + jg * 32 + 8 * l4);        \
                _Pragma("unroll")                                                    \
                for (int it = 0; it < 4; it++)                                       \
                    acc[ct][it] = mfma16(vf, pcf[it], acc[ct][it]);                  \
            }                                                                        \
        }                                                                            \
    }

    short8 kf0 = *(const short8*)(kb + (size_t)(w * 32 + l15) * 32 + 8 * l4);
    short8 kf1 = *(const short8*)(kb + (size_t)(w * 32 + 16 + l15) * 32 + 8 * l4);
    PROD(0, kf0, kf1);

#pragma unroll 1
    for (int t = 0; t < 31; t++) {
        __syncthreads();
        const int jj = (t + 1) * 128 + w * 32;
        short8 nk0 = *(const short8*)(kb + (size_t)(jj + l15) * 32 + 8 * l4);
        short8 nk1 = *(const short8*)(kb + (size_t)(jj + 16 + l15) * 32 + 8 * l4);
        CONSUME(t);
        PROD(t + 1, nk0, nk1);
    }
    __syncthreads();
    CONSUME(31);
#undef PROD
#undef CONSUME

#pragma unroll
    for (int it = 0; it < 4; it++) {
        l_[it] += __shfl_xor(l_[it], 16, 64);
        l_[it] += __shfl_xor(l_[it], 32, 64);
    }
    if (lane < 16)
#pragma unroll
        for (int it = 0; it < 4; it++) red_lds[w * 64 + it * 16 + lane] = l_[it];
    __syncthreads();

    const float g = gamma[0];
    float inv[4];
#pragma unroll
    for (int it = 0; it < 4; it++) {
        float s = 0.0f;
#pragma unroll
        for (int ww = 0; ww < 4; ww++) s += red_lds[ww * 64 + it * 16 + l15];
        inv[it] = g / s;
    }

#pragma unroll
    for (int ct = 0; ct < 4; ct++)
#pragma unroll
        for (int it = 0; it < 4; it++)
#pragma unroll
            for (int r = 0; r < 4; r++) {
                const int c = cb + ct * 16 + 4 * l4 + r;
                const int i = i0 + it * 16 + l15;
                const size_t o = ((size_t)(b * 512 + c)) * 4096 + i;
                out[o] = acc[ct][it][r] * inv[it] + x[o];
            }
}

extern "C" void kernel_launch(void* const* d_in, const int* in_sizes, int n_in,
                              void* d_out, int out_size, void* d_ws, size_t ws_size,
                              hipStream_t stream) {
    const float* x     = (const float*)d_in[0];
    const float* wq    = (const float*)d_in[1];
    const float* bq    = (const float*)d_in[2];
    const float* wk    = (const float*)d_in[3];
    const float* bk    = (const float*)d_in[4];
    const float* wv    = (const float*)d_in[5];
    const float* bv    = (const float*)d_in[6];
    const float* gamma = (const float*)d_in[7];
    float* out = (float*)d_out;

    short* qT = (short*)d_ws;                  // 1 MB
    short* kT = qT + (size_t)4 * 4096 * 32;    // 1 MB
    short* vm = kT + (size_t)4 * 4096 * 32;    // 16 MB
    short* wb = vm + (size_t)4 * 512 * 4096;   // 0.56 MB

    wcvt_kernel<<<288, 256, 0, stream>>>(wq, wk, wv, wb);
    proj_kernel<<<dim3(64, 3, 4), 256, 0, stream>>>(x, wb, bq, bk, bv, qT, kT, vm);
    attn_kernel<<<512, 256, 0, stream>>>(qT, kT, vm, x, gamma, out);
}